// Round 20
// baseline (26.850 us; speedup 1.0000x reference)
//
#include <hip/hip_runtime.h>

#define BB 8
#define NN 256
#define DD 128
#define LN_EPS 1e-5f

// ---------------------------------------------------------------------------
// k_proj: hi = x @ w1[:D],  hjb = x @ w1[D:] + b1   (R19 verbatim)
// grid 256 blocks (8 rows) x 1024 threads (16 waves/CU = 4/SIMD).
// ---------------------------------------------------------------------------
__global__ __launch_bounds__(1024, 4) void k_proj(const float* __restrict__ x,
                                                  const float* __restrict__ w1,
                                                  const float* __restrict__ b1,
                                                  float* __restrict__ hi,
                                                  float* __restrict__ hjb) {
    __shared__ float xs[8 * DD];       // 4 KB
    __shared__ float part[16384];      // 64 KB: A @0, B @8192
    const int bid  = blockIdx.x;
    const int row0 = (bid & 7) * NN + (bid >> 3) * 8;   // XCD-affine
    const int tid  = threadIdx.x;
    xs[tid] = x[row0 * DD + tid];      // 1024 = 8*128 exactly
    __syncthreads();

    const int dp = tid & 127;
    const int kg = tid >> 7;     // 0..7
    const int kb = kg * 16;

    float aA[8] = {}, aB[8] = {};
    #pragma unroll
    for (int k4 = 0; k4 < 4; ++k4) {
        const int k0 = kb + k4 * 4;
        float wa[4], wb[4];
        #pragma unroll
        for (int q = 0; q < 4; ++q) {
            wa[q] = w1[(k0 + q) * DD + dp];
            wb[q] = w1[(DD + k0 + q) * DD + dp];
        }
        #pragma unroll
        for (int r = 0; r < 8; ++r) {
            const float4 xv = *(const float4*)&xs[r * DD + k0];  // broadcast
            aA[r] = fmaf(xv.x, wa[0], aA[r]);
            aA[r] = fmaf(xv.y, wa[1], aA[r]);
            aA[r] = fmaf(xv.z, wa[2], aA[r]);
            aA[r] = fmaf(xv.w, wa[3], aA[r]);
            aB[r] = fmaf(xv.x, wb[0], aB[r]);
            aB[r] = fmaf(xv.y, wb[1], aB[r]);
            aB[r] = fmaf(xv.z, wb[2], aB[r]);
            aB[r] = fmaf(xv.w, wb[3], aB[r]);
        }
    }
    #pragma unroll
    for (int r = 0; r < 8; ++r) {
        part[kg * 1024 + r * DD + dp]        = aA[r];
        part[8192 + kg * 1024 + r * DD + dp] = aB[r];
    }
    __syncthreads();
    {
        int r = tid >> 7, d = tid & 127;
        float sa = 0.f, sb = 0.f;
        #pragma unroll
        for (int w = 0; w < 8; ++w) {
            sa += part[w * 1024 + r * DD + d];
            sb += part[8192 + w * 1024 + r * DD + d];
        }
        hi [(row0 + r) * DD + d] = sa;
        hjb[(row0 + r) * DD + d] = sb + b1[d];
    }
}

// ---------------------------------------------------------------------------
// k_fused: R19 shell at 1024 threads; pair swapped to transposed-adjacency
// form: a_tt[256][8] (1 b128 = 4 rows' a), 4 rows x 4 d per thread, 16-way
// j-split (16 j/thread) -> pair LDS wave-instrs 2048 -> 512. Partials commit
// in two phases (waves 0-7 then 8-15) to fit the 8K-float hjs alias region.
// Tail = R19 verbatim (1 col/thread, 8-way k-split).
// smem floats: [0,8192) hjs / partP[8][1024] / partT[8][1024]
//   [8192,10240) a_tt[256][8]; aliases u1s@8192, resS@9216 after pair
//   [10240,11264) xs | [11264,12288) ssp | [12288,13312) aggs
//   [13312,13344) asub[8][4] | [13344,13352) asum_s
// ---------------------------------------------------------------------------
__global__ __launch_bounds__(1024, 4) void k_fused(const float* __restrict__ adj,
                                                   const float* __restrict__ x,
                                                   const float* __restrict__ hi,
                                                   const float* __restrict__ hjb,
                                                   const float* __restrict__ w2,
                                                   const float* __restrict__ b2,
                                                   const float* __restrict__ w3,
                                                   const float* __restrict__ b3,
                                                   const float* __restrict__ w4,
                                                   const float* __restrict__ b4,
                                                   const float* __restrict__ g,
                                                   const float* __restrict__ bet,
                                                   float* __restrict__ out) {
    __shared__ float smem[13352];
    float* const hjs    = smem;           // [64][128]
    float* const partP  = smem;           // [8][1024] alias
    float* const partT  = smem;           // [8][1024] alias
    float* const a_tt   = smem + 8192;    // [256][8]
    float* const u1s    = smem + 8192;    // [8][128] alias (a_tt dead)
    float* const resS   = smem + 9216;    // [8][128] alias
    float* const xs     = smem + 10240;   // [8][128]
    float* const ssp    = smem + 11264;   // [8][128]
    float* const aggs   = smem + 12288;   // [8][128]
    float* const asub   = smem + 13312;   // [8][4]
    float* const asum_s = smem + 13344;   // [8]

    const int bid  = blockIdx.x;
    const int b    = bid & 7;             // XCD-affine batch
    const int i0   = (bid >> 3) * 8;
    const int tid  = threadIdx.x;
    const int lane = tid & 63;
    const int wv   = tid >> 6;            // 0..15

    // ---- stage transposed masked adjacency + asum partials via shfl
    #pragma unroll
    for (int t = 0; t < 2; ++t) {
        int idx = tid + t * 1024;           // 0..2047
        int il = idx >> 8, j = idx & 255;   // il wave-uniform
        int ig = i0 + il;
        float av = adj[((size_t)b * NN + ig) * NN + j];
        av = (j == ig) ? 0.f : av;
        a_tt[j * 8 + il] = av;
        float s = av;
        #pragma unroll
        for (int m = 32; m; m >>= 1) s += __shfl_xor(s, m);
        if (lane == 0) asub[il * 4 + ((idx >> 6) & 3)] = s;
    }
    // ---- stage x rows
    xs[tid] = x[((size_t)b * NN + i0) * DD + tid];

    // ---- per-thread hi fragments: 4 rows x 4 d
    const int dq = lane & 31;        // d-quad (d0 = dq*4)
    const int rh = lane >> 5;        // rows rh*4 .. rh*4+3
    float4 hi4[4];
    #pragma unroll
    for (int rr = 0; rr < 4; ++rr)
        hi4[rr] = *(const float4*)&hi[((size_t)b * NN + i0 + rh * 4 + rr) * DD + dq * 4];
    float4 acc[4] = {{0,0,0,0},{0,0,0,0},{0,0,0,0},{0,0,0,0}};

    // ---- pair: 4 tiles of 64 j; wave wv covers j [wv*4, wv*4+4) per tile
    for (int jt = 0; jt < 4; ++jt) {
        __syncthreads();   // staging visible / prev tile reads done
        const float4* src = (const float4*)(hjb + ((size_t)b * NN + jt * 64) * DD);
        float4* dst = (float4*)hjs;
        #pragma unroll
        for (int t = 0; t < 2; ++t) dst[tid + t * 1024] = src[tid + t * 1024];
        __syncthreads();
        const int jb = wv * 4;
        #pragma unroll
        for (int jj = 0; jj < 4; ++jj) {
            const int jl = jb + jj;
            const float4 hv = *(const float4*)&hjs[jl * DD + dq * 4];
            const float4 a4 = *(const float4*)&a_tt[(jt * 64 + jl) * 8 + rh * 4];
            const float aa[4] = {a4.x, a4.y, a4.z, a4.w};
            #pragma unroll
            for (int rr = 0; rr < 4; ++rr) {
                acc[rr].x = fmaf(fmaxf(hi4[rr].x + hv.x, 0.f), aa[rr], acc[rr].x);
                acc[rr].y = fmaf(fmaxf(hi4[rr].y + hv.y, 0.f), aa[rr], acc[rr].y);
                acc[rr].z = fmaf(fmaxf(hi4[rr].z + hv.z, 0.f), aa[rr], acc[rr].z);
                acc[rr].w = fmaf(fmaxf(hi4[rr].w + hv.w, 0.f), aa[rr], acc[rr].w);
            }
        }
    }
    __syncthreads();       // last hjs reads done before partP alias writes

    // ---- partials, two phases (waves 0-7 then 8-15); finalize asum
    if (wv < 8) {
        float* pp = partP + wv * 1024 + rh * 4 * DD;
        #pragma unroll
        for (int rr = 0; rr < 4; ++rr)
            *(float4*)&pp[rr * DD + dq * 4] = acc[rr];
    }
    __syncthreads();
    if (tid < 8)
        asum_s[tid] = asub[tid * 4] + asub[tid * 4 + 1]
                    + asub[tid * 4 + 2] + asub[tid * 4 + 3];
    {
        float s = 0.f;
        #pragma unroll
        for (int w = 0; w < 8; ++w) s += partP[w * 1024 + tid];
        ssp[tid] = s;
    }
    __syncthreads();
    if (wv >= 8) {
        float* pp = partP + (wv - 8) * 1024 + rh * 4 * DD;
        #pragma unroll
        for (int rr = 0; rr < 4; ++rr)
            *(float4*)&pp[rr * DD + dq * 4] = acc[rr];
    }
    __syncthreads();
    {
        float s = ssp[tid];
        #pragma unroll
        for (int w = 0; w < 8; ++w) s += partP[w * 1024 + tid];
        ssp[tid] = s;
    }
    __syncthreads();

    // ---- tail: 1 col/thread (dp), 8-way k-split (kg), 16 k each (R19)
    const int dp = tid & 127;
    const int kg = tid >> 7;            // 0..7
    const int kb = kg * 16;

    // stage A: agg = ssp @ w2 (+ b2*asum at combine)
    {
        float w0[16];
        #pragma unroll
        for (int k = 0; k < 16; ++k) w0[k] = w2[(kb + k) * DD + dp];
        #pragma unroll
        for (int r = 0; r < 8; ++r) {
            float a0 = 0.f;
            #pragma unroll
            for (int q = 0; q < 4; ++q) {
                const float4 sv = *(const float4*)&ssp[r * 128 + kb + q * 4];
                a0 = fmaf(sv.x, w0[q*4+0], a0);
                a0 = fmaf(sv.y, w0[q*4+1], a0);
                a0 = fmaf(sv.z, w0[q*4+2], a0);
                a0 = fmaf(sv.w, w0[q*4+3], a0);
            }
            partT[kg * 1024 + r * 128 + dp] = a0;
        }
    }
    __syncthreads();
    {
        int r = tid >> 7, d = tid & 127;
        float s = 0.f;
        #pragma unroll
        for (int w = 0; w < 8; ++w) s += partT[w * 1024 + tid];
        aggs[tid] = s + b2[d] * asum_s[r];
    }
    __syncthreads();

    // stage B: u1 = relu(x@w3a + agg@w3b + b3)
    {
        float wa0[16], wb0[16];
        #pragma unroll
        for (int k = 0; k < 16; ++k) {
            wa0[k] = w3[(kb + k) * DD + dp];
            wb0[k] = w3[(DD + kb + k) * DD + dp];
        }
        #pragma unroll
        for (int r = 0; r < 8; ++r) {
            float a0 = 0.f;
            #pragma unroll
            for (int q = 0; q < 4; ++q) {
                const float4 xv = *(const float4*)&xs[r * 128 + kb + q * 4];
                const float4 av = *(const float4*)&aggs[r * 128 + kb + q * 4];
                a0 = fmaf(xv.x, wa0[q*4+0], a0);
                a0 = fmaf(xv.y, wa0[q*4+1], a0);
                a0 = fmaf(xv.z, wa0[q*4+2], a0);
                a0 = fmaf(xv.w, wa0[q*4+3], a0);
                a0 = fmaf(av.x, wb0[q*4+0], a0);
                a0 = fmaf(av.y, wb0[q*4+1], a0);
                a0 = fmaf(av.z, wb0[q*4+2], a0);
                a0 = fmaf(av.w, wb0[q*4+3], a0);
            }
            partT[kg * 1024 + r * 128 + dp] = a0;
        }
    }
    __syncthreads();
    {
        int d = tid & 127;
        float s = 0.f;
        #pragma unroll
        for (int w = 0; w < 8; ++w) s += partT[w * 1024 + tid];
        u1s[tid] = fmaxf(s + b3[d], 0.f);
    }
    __syncthreads();

    // stage C: upd = u1 @ w4; res = x + upd + b4
    {
        float w0[16];
        #pragma unroll
        for (int k = 0; k < 16; ++k) w0[k] = w4[(kb + k) * DD + dp];
        #pragma unroll
        for (int r = 0; r < 8; ++r) {
            float a0 = 0.f;
            #pragma unroll
            for (int q = 0; q < 4; ++q) {
                const float4 uv = *(const float4*)&u1s[r * 128 + kb + q * 4];
                a0 = fmaf(uv.x, w0[q*4+0], a0);
                a0 = fmaf(uv.y, w0[q*4+1], a0);
                a0 = fmaf(uv.z, w0[q*4+2], a0);
                a0 = fmaf(uv.w, w0[q*4+3], a0);
            }
            partT[kg * 1024 + r * 128 + dp] = a0;
        }
    }
    __syncthreads();
    {
        int d = tid & 127;
        float s = xs[tid] + b4[d];
        #pragma unroll
        for (int w = 0; w < 8; ++w) s += partT[w * 1024 + tid];
        resS[tid] = s;
    }
    __syncthreads();

    // ---- LayerNorm: waves 0..7, one row each, 2 d's per lane
    if (tid < 512) {
        const int r = tid >> 6, l = tid & 63;
        const float2 v = *(const float2*)&resS[r * 128 + l * 2];
        float s1 = v.x + v.y;
        float s2 = v.x * v.x + v.y * v.y;
        #pragma unroll
        for (int m = 32; m; m >>= 1) {
            s1 += __shfl_xor(s1, m);
            s2 += __shfl_xor(s2, m);
        }
        const float mu = s1 * (1.f / DD);
        const float rs = rsqrtf(s2 * (1.f / DD) - mu * mu + LN_EPS);
        const int d = l * 2;
        const float2 gv = *(const float2*)&g[d];
        const float2 bv = *(const float2*)&bet[d];
        float2 o;
        o.x = (v.x - mu) * rs * gv.x + bv.x;
        o.y = (v.y - mu) * rs * gv.y + bv.y;
        *(float2*)&out[((size_t)b * NN + i0 + r) * DD + d] = o;
    }
}

extern "C" void kernel_launch(void* const* d_in, const int* in_sizes, int n_in,
                              void* d_out, int out_size, void* d_ws, size_t ws_size,
                              hipStream_t stream) {
    (void)in_sizes; (void)n_in; (void)out_size; (void)ws_size;
    const float* x      = (const float*)d_in[0];
    const float* adj    = (const float*)d_in[1];
    const float* msg_w1 = (const float*)d_in[2];
    const float* msg_b1 = (const float*)d_in[3];
    const float* msg_w2 = (const float*)d_in[4];
    const float* msg_b2 = (const float*)d_in[5];
    const float* upd_w1 = (const float*)d_in[6];
    const float* upd_b1 = (const float*)d_in[7];
    const float* upd_w2 = (const float*)d_in[8];
    const float* upd_b2 = (const float*)d_in[9];
    const float* ln_g   = (const float*)d_in[10];
    const float* ln_b   = (const float*)d_in[11];
    float* out = (float*)d_out;

    const size_t BND = (size_t)BB * NN * DD;
    float* ws  = (float*)d_ws;
    float* hi  = ws;            // B*N*D
    float* hjb = ws + BND;      // B*N*D

    k_proj<<<dim3(256), dim3(1024), 0, stream>>>(x, msg_w1, msg_b1, hi, hjb);
    k_fused<<<dim3(256), dim3(1024), 0, stream>>>(adj, x, hi, hjb,
                                                  msg_w2, msg_b2,
                                                  upd_w1, upd_b1, upd_w2, upd_b2,
                                                  ln_g, ln_b, out);
}